// Round 13
// baseline (385.831 us; speedup 1.0000x reference)
//
#include <hip/hip_runtime.h>

#define HW 16384   // 128*128

typedef _Float16 half8  __attribute__((ext_vector_type(8)));
typedef _Float16 half4v __attribute__((ext_vector_type(4)));
typedef float    f32x4  __attribute__((ext_vector_type(4)));

typedef __attribute__((address_space(3))) unsigned int lds_u32;
typedef const __attribute__((address_space(1))) unsigned int glb_u32;

// direct global->LDS 16B DMA (no VGPR round trip)
__device__ __forceinline__ void gl_lds16(const void* g, void* l) {
    __builtin_amdgcn_global_load_lds((glb_u32*)g, (lds_u32*)l, 16, 0, 0);
}

// ---------------- zero fill (float4 granularity) ----------------
__global__ void zero4(float4* __restrict__ p, int n4) {
    int i = blockIdx.x * 256 + threadIdx.x;
    if (i < n4) p[i] = make_float4(0.f, 0.f, 0.f, 0.f);
}

__global__ void write_code_f32(float* out, float v) {
    if (threadIdx.x == 0 && blockIdx.x == 0) out[0] = v;
}

// ---------------- weight pack: OIDHW f32 -> A-fragment-ordered f16 ----------------
// dst[((grp*NSTEPS+s)*64+lane)*8+j] = W[co=grp*16+(lane&15)][k=s*32+(lane>>4)*8+j]
// k = tap*CINp + ci, tap = (dz*KHW+dy)*KHW+dx ; ci >= CINr -> 0
__global__ void pack_w(const float* __restrict__ W, _Float16* __restrict__ dst,
                       int CINr, int CINp, int COUT, int KD, int KHW, int NSTEPS) {
    int idx = blockIdx.x * 256 + threadIdx.x;
    int total = (COUT / 16) * NSTEPS * 64;
    if (idx >= total) return;
    int lane = idx & 63;
    int s    = (idx >> 6) % NSTEPS;
    int grp  = idx / (NSTEPS * 64);
    int k0  = s * 32 + (lane >> 4) * 8;
    int t   = k0 / CINp;
    int ci0 = k0 % CINp;
    int co  = grp * 16 + (lane & 15);
    int khw2 = KHW * KHW;
    int dz = t / khw2, r = t % khw2, dy = r / KHW, dx = r % KHW;
    half8 hv;
    for (int j = 0; j < 8; ++j) {
        int ci = ci0 + j;
        float wv = (ci < CINr)
            ? W[(((size_t)co * CINr + ci) * KD + dz) * khw2 + dy * KHW + dx] : 0.0f;
        hv[j] = (_Float16)wv;
    }
    *(half8*)(dst + ((size_t)(grp * NSTEPS + s) * 64 + lane) * 8) = hv;
}

// ---------------- scatter voxels into [z][130][130][40] f16 grid ----------------
__global__ void scatter_f16(const float* __restrict__ vf, const int* __restrict__ coors,
                            _Float16* __restrict__ act, unsigned char* __restrict__ occ, int n) {
    int i = blockIdx.x * 256 + threadIdx.x;
    if (i >= n) return;
    int z = coors[i * 4 + 1];
    int y = coors[i * 4 + 2];
    int x = coors[i * 4 + 3];
    size_t cell = ((size_t)(z * 130 + (y + 1)) * 130 + (x + 1)) * 40;
    for (int c = 0; c < 16; ++c) act[cell + c] = (_Float16)vf[i * 16 + c];
    occ[z * HW + y * 128 + x] = 1;
}

// ---------------- pool occupancy (u8) over z: D16 -> D8 -> D4 -> D2 ----------------
__global__ void pool_occ(const unsigned char* __restrict__ o0, unsigned char* __restrict__ o1,
                         unsigned char* __restrict__ o2, unsigned char* __restrict__ o3) {
    int p = blockIdx.x * 256 + threadIdx.x;
    if (p >= HW) return;
    unsigned char a[16];
    for (int z = 0; z < 16; ++z) a[z] = o0[z * HW + p];
    for (int z = 0; z < 8; ++z) { a[z] = a[2 * z] | a[2 * z + 1]; o1[z * HW + p] = a[z]; }
    for (int z = 0; z < 4; ++z) { a[z] = a[2 * z] | a[2 * z + 1]; o2[z * HW + p] = a[z]; }
    for (int z = 0; z < 2; ++z) { a[z] = a[2 * z] | a[2 * z + 1]; o3[z * HW + p] = a[z]; }
}

// ---------------- MFMA implicit-GEMM conv + BN + ReLU + occ ----------------
// act : [DIN][130][130][CS=CINp+8] f16 (y/x padded by 1; border cells' real
//       channels are zero; pad channels never read by compute).
// Staging: global_load_lds 16B granules, LDS [4 rows][66 cols][CS] == linear
//          copy of the 4x66 window (x-tiled: 64 output px + 2 halo cols).
// out : intermediate [DOUT][130][130][COUT+8] f16 ; FINAL [COUT*2][128][128] f32
// block: 2 waves = 2 output rows x 64 px (x-tile xb), each wave = 64 cout x 64 px.
// 38 KB LDS -> 4 blocks/CU: 4 independent stage/compute streams per CU.
template <int CINp, int COUT, int KD, int KHW, int SZ, int DIN, int DOUT, bool FINAL>
__global__ __launch_bounds__(128, 2)
void conv_mfma(const _Float16* __restrict__ act, const _Float16* __restrict__ apack,
               const float* __restrict__ gm, const float* __restrict__ bt,
               const float* __restrict__ mn, const float* __restrict__ vr,
               const unsigned char* __restrict__ occ, void* __restrict__ outv) {
    constexpr int PADXY  = KHW / 2;
    constexpr int CB     = CINp / 32;           // 32-k blocks per tap
    constexpr int MG     = COUT / 16;           // co-groups per wave
    constexpr int NSTEPS = KD * KHW * KHW * CB; // total K-steps (for A indexing)
    constexpr int CS     = CINp + 8;            // cell stride (global AND LDS)
    constexpr int OCS    = COUT + 8;            // output cell stride
    constexpr int RG     = 66 * CS / 8;         // 16B granules per staged row
    constexpr int NGRAN  = 4 * RG;              // granules per 4x66 window
    constexpr int NIT    = (NGRAN + 127) / 128;
    constexpr int OFS    = 1 - PADXY;           // tap offset correction

    __shared__ _Float16 smem[4 * 66 * CS];

    const int bid = blockIdx.x;
    const int xb = bid & 1;
    const int yp = (bid >> 1) & 63;
    const int z0 = bid >> 7;
    const int y0 = yp * 2;
    const int tid  = threadIdx.x;
    const int w    = tid >> 6;
    const int lane = tid & 63;
    const int ylocal = w;            // 0..1
    const int n  = lane & 15;
    const int kg = lane >> 4;

    f32x4 acc[MG][4];
    #pragma unroll
    for (int m = 0; m < MG; ++m)
        #pragma unroll
        for (int t = 0; t < 4; ++t) { acc[m][t][0] = 0.f; acc[m][t][1] = 0.f; acc[m][t][2] = 0.f; acc[m][t][3] = 0.f; }

    const int zb = z0 * SZ;
    const int dzlo = (zb == 0) ? 1 : 0;
    const int dzhi = (zb + KD - 1 > DIN) ? (KD - 1) : KD;

    for (int dz = dzlo; dz < dzhi; ++dz) {
        const int zi = zb + dz - 1;
        __syncthreads();   // previous iteration's LDS reads complete
        // ---- stage 4x66 window via global_load_lds ----
        #pragma unroll
        for (int it = 0; it < NIT; ++it) {
            int g = it * 128 + tid;
            if (g < NGRAN) {
                int row = g / RG;
                int rg  = g - row * RG;
                const _Float16* src = act
                    + ((size_t)(zi * 130 + y0 + row) * 130 + xb * 64) * CS + (size_t)rg * 8;
                gl_lds16(src, smem + (size_t)g * 8);
            }
        }
        asm volatile("s_waitcnt vmcnt(0)" ::: "memory");
        __syncthreads();
        // ---- K-loop over taps (straight-line) ----
        #pragma unroll
        for (int dy = 0; dy < KHW; ++dy) {
            #pragma unroll
            for (int dx = 0; dx < KHW; ++dx) {
                #pragma unroll
                for (int cb = 0; cb < CB; ++cb) {
                    const int sabs = dz * (KHW * KHW * CB) + (dy * KHW + dx) * CB + cb;
                    half8 a[MG];
                    #pragma unroll
                    for (int mg = 0; mg < MG; ++mg)
                        a[mg] = *(const half8*)(apack + ((size_t)(mg * NSTEPS + sabs) * 64 + lane) * 8);
                    const _Float16* bp = smem
                        + ((ylocal + dy + OFS) * 66 + n + dx + OFS) * CS + cb * 32 + kg * 8;
                    #pragma unroll
                    for (int nt = 0; nt < 4; ++nt) {
                        half8 b = *(const half8*)(bp + nt * 16 * CS);
                        #pragma unroll
                        for (int mg = 0; mg < MG; ++mg)
                            acc[mg][nt] = __builtin_amdgcn_mfma_f32_16x16x32_f16(a[mg], b, acc[mg][nt], 0, 0, 0);
                    }
                }
            }
        }
    }

    // ---- epilogue: BN + ReLU + occ, store ----
    const int yo = y0 + ylocal;
    #pragma unroll
    for (int mg = 0; mg < MG; ++mg) {
        const int co0 = mg * 16 + kg * 4;
        const f32x4 gv = *(const f32x4*)(gm + co0);
        const f32x4 bv = *(const f32x4*)(bt + co0);
        const f32x4 mv = *(const f32x4*)(mn + co0);
        const f32x4 vv = *(const f32x4*)(vr + co0);
        float sc[4], sh[4];
        #pragma unroll
        for (int r = 0; r < 4; ++r) {
            sc[r] = gv[r] * __frsqrt_rn(vv[r] + 1e-5f);
            sh[r] = bv[r] - mv[r] * sc[r];
        }
        #pragma unroll
        for (int nt = 0; nt < 4; ++nt) {
            const int x = xb * 64 + nt * 16 + n;
            const float occv = (float)occ[z0 * HW + yo * 128 + x];
            float v0 = fmaxf(fmaf(acc[mg][nt][0], sc[0], sh[0]), 0.f) * occv;
            float v1 = fmaxf(fmaf(acc[mg][nt][1], sc[1], sh[1]), 0.f) * occv;
            float v2 = fmaxf(fmaf(acc[mg][nt][2], sc[2], sh[2]), 0.f) * occv;
            float v3 = fmaxf(fmaf(acc[mg][nt][3], sc[3], sh[3]), 0.f) * occv;
            if constexpr (FINAL) {
                float* o = (float*)outv;
                const int sp = yo * 128 + x;
                o[((size_t)(co0 + 0) * 2 + z0) * HW + sp] = v0;
                o[((size_t)(co0 + 1) * 2 + z0) * HW + sp] = v1;
                o[((size_t)(co0 + 2) * 2 + z0) * HW + sp] = v2;
                o[((size_t)(co0 + 3) * 2 + z0) * HW + sp] = v3;
            } else {
                _Float16* o = (_Float16*)outv;
                half4v hv;
                hv[0] = (_Float16)v0; hv[1] = (_Float16)v1;
                hv[2] = (_Float16)v2; hv[3] = (_Float16)v3;
                *(half4v*)(o + ((size_t)(z0 * 130 + (yo + 1)) * 130 + (x + 1)) * OCS + co0) = hv;
            }
        }
    }
}

extern "C" void kernel_launch(void* const* d_in, const int* in_sizes, int n_in,
                              void* d_out, int out_size, void* d_ws, size_t ws_size,
                              hipStream_t stream) {
    const float* vf    = (const float*)d_in[0];
    const int*   coors = (const int*)d_in[1];
    const float* w0    = (const float*)d_in[2];
    const float* w1    = (const float*)d_in[3];
    const float* w2    = (const float*)d_in[4];
    const float* w64   = (const float*)d_in[5];
    const float* w10   = (const float*)d_in[6];
    const float* g32   = (const float*)d_in[7];
    const float* b32   = (const float*)d_in[8];
    const float* m32   = (const float*)d_in[9];
    const float* v32   = (const float*)d_in[10];
    const float* g64   = (const float*)d_in[11];
    const float* b64   = (const float*)d_in[12];
    const float* m64   = (const float*)d_in[13];
    const float* v64   = (const float*)d_in[14];
    const int N = in_sizes[0] / 16;

    float* out_f = (float*)d_out;

    // ---- workspace layout (bytes) ----
    // S32   = 16*130*130*40*2 = 21,632,000  (P32 layers, D16)
    // S64_8 =  8*130*130*72*2 = 19,468,800  (P64 layers, D8)
    // S64_4 =  4*130*130*72*2 =  9,734,400  (P64 layers, D4)
    // R2 aliases R1 (P32 dead after L1); D4A/D4B alias R0/R1 fronts.
    const size_t R0 = 0;
    const size_t R1 = 21632000;
    const size_t R3 = 43264000;
    const size_t OFF_OCC0 = 62732800;   // u8 [16][HW]
    const size_t OFF_OCC1 = 62994944;   // u8 [8][HW]
    const size_t OFF_OCC2 = 63126016;   // u8 [4][HW]
    const size_t OFF_OCC3 = 63191552;   // u8 [2][HW]
    const size_t OFF_AP   = 63224320;   // f16 packed weights (897,024 el)
    const size_t TOTAL_BYTES = 65018368;
    const size_t S64_8 = 19468800;
    const size_t S64_4 = 9734400;

    if (ws_size < TOTAL_BYTES) {
        write_code_f32<<<dim3(1), dim3(64), 0, stream>>>(out_f, 1.0e8f);
        return;
    }

    char* wsb = (char*)d_ws;
    _Float16* A0p = (_Float16*)(wsb + R0);   // P32 A ; front = D4A
    _Float16* A1p = (_Float16*)(wsb + R1);   // P32 B ; also R2 (P64 D8) ; front = D4B
    _Float16* A3p = (_Float16*)(wsb + R3);   // P64 D8
    _Float16* A2p = A1p;                     // R2 alias
    unsigned char* occ0 = (unsigned char*)(wsb + OFF_OCC0);
    unsigned char* occ1 = (unsigned char*)(wsb + OFF_OCC1);
    unsigned char* occ2 = (unsigned char*)(wsb + OFF_OCC2);
    unsigned char* occ3 = (unsigned char*)(wsb + OFF_OCC3);
    _Float16* AP = (_Float16*)(wsb + OFF_AP);

    const size_t W_A0 = 0, W_A1 = 27648, W_A2 = 55296, W_A3 = 110592, W_A10 = 884736;

    // zero R0..occ0 end (covers R0, R1, R3, occ0)
    {
        const int n4 = (int)(OFF_OCC1 / 16);
        zero4<<<dim3((n4 + 255) / 256), dim3(256), 0, stream>>>((float4*)wsb, n4);
    }

    auto pk = [&](const float* src, size_t dstoff, int cinr, int cinp, int cout, int kd, int khw) {
        int nsteps = kd * khw * khw * (cinp / 32);
        int total = (cout / 16) * nsteps * 64;
        pack_w<<<dim3((total + 255) / 256), dim3(256), 0, stream>>>(
            src, AP + dstoff, cinr, cinp, cout, kd, khw, nsteps);
    };
    pk(w0, W_A0, 16, 32, 32, 3, 3);
    pk(w1, W_A1, 32, 32, 32, 3, 3);
    pk(w2, W_A2, 32, 32, 64, 3, 3);
    for (int i = 0; i < 7; ++i)
        pk(w64 + (size_t)i * 110592, W_A3 + (size_t)i * 110592, 64, 64, 64, 3, 3);
    pk(w10, W_A10, 64, 64, 64, 3, 1);

    scatter_f16<<<dim3((N + 255) / 256), dim3(256), 0, stream>>>(vf, coors, A0p, occ0, N);
    pool_occ<<<dim3(HW / 256), dim3(256), 0, stream>>>(occ0, occ1, occ2, occ3);

    // L0: 16(pad32)->32, D16  (R0 -> R1)
    conv_mfma<32, 32, 3, 3, 1, 16, 16, false><<<dim3(16 * 128), dim3(128), 0, stream>>>(
        A0p, AP + W_A0, g32, b32, m32, v32, occ0, A1p);
    // L1: 32->32, D16  (R1 -> R0)
    conv_mfma<32, 32, 3, 3, 1, 16, 16, false><<<dim3(16 * 128), dim3(128), 0, stream>>>(
        A1p, AP + W_A1, g32 + 32, b32 + 32, m32 + 32, v32 + 32, occ0, A0p);
    // R1's P32 data dead -> zero R2 region (P64 D8 borders must be 0)
    zero4<<<dim3((int)(S64_8 / 16 + 255) / 256, 1, 1), dim3(256), 0, stream>>>((float4*)A2p, (int)(S64_8 / 16));
    // L2: 32->64, stride-z 2, D16->8  (R0 -> R2)
    conv_mfma<32, 64, 3, 3, 2, 16, 8, false><<<dim3(8 * 128), dim3(128), 0, stream>>>(
        A0p, AP + W_A2, g64, b64, m64, v64, occ1, A2p);
    // R0 dead -> zero D4A front
    zero4<<<dim3((int)(S64_4 / 16 + 255) / 256, 1, 1), dim3(256), 0, stream>>>((float4*)A0p, (int)(S64_4 / 16));
    // L3..L5: 64->64, D8  (R2 -> R3 -> R2 -> R3)
    conv_mfma<64, 64, 3, 3, 1, 8, 8, false><<<dim3(8 * 128), dim3(128), 0, stream>>>(
        A2p, AP + W_A3 + 0 * 110592, g64 + 64, b64 + 64, m64 + 64, v64 + 64, occ1, A3p);
    conv_mfma<64, 64, 3, 3, 1, 8, 8, false><<<dim3(8 * 128), dim3(128), 0, stream>>>(
        A3p, AP + W_A3 + 1 * 110592, g64 + 128, b64 + 128, m64 + 128, v64 + 128, occ1, A2p);
    conv_mfma<64, 64, 3, 3, 1, 8, 8, false><<<dim3(8 * 128), dim3(128), 0, stream>>>(
        A2p, AP + W_A3 + 2 * 110592, g64 + 192, b64 + 192, m64 + 192, v64 + 192, occ1, A3p);
    // L6: 64->64, stride-z 2, D8->4  (R3 -> D4A)
    conv_mfma<64, 64, 3, 3, 2, 8, 4, false><<<dim3(4 * 128), dim3(128), 0, stream>>>(
        A3p, AP + W_A3 + 3 * 110592, g64 + 256, b64 + 256, m64 + 256, v64 + 256, occ2, A0p);
    // R2 dead (after L5) -> zero D4B front
    zero4<<<dim3((int)(S64_4 / 16 + 255) / 256, 1, 1), dim3(256), 0, stream>>>((float4*)A1p, (int)(S64_4 / 16));
    // L7..L9: 64->64, D4  (D4A -> D4B -> D4A -> D4B)
    conv_mfma<64, 64, 3, 3, 1, 4, 4, false><<<dim3(4 * 128), dim3(128), 0, stream>>>(
        A0p, AP + W_A3 + 4 * 110592, g64 + 320, b64 + 320, m64 + 320, v64 + 320, occ2, A1p);
    conv_mfma<64, 64, 3, 3, 1, 4, 4, false><<<dim3(4 * 128), dim3(128), 0, stream>>>(
        A1p, AP + W_A3 + 5 * 110592, g64 + 384, b64 + 384, m64 + 384, v64 + 384, occ2, A0p);
    conv_mfma<64, 64, 3, 3, 1, 4, 4, false><<<dim3(4 * 128), dim3(128), 0, stream>>>(
        A0p, AP + W_A3 + 6 * 110592, g64 + 448, b64 + 448, m64 + 448, v64 + 448, occ2, A1p);
    // L10: 64->64, kernel (3,1,1), stride-z 2, D4->2, f32 out -> d_out  (D4B -> out)
    conv_mfma<64, 64, 3, 1, 2, 4, 2, true><<<dim3(2 * 128), dim3(128), 0, stream>>>(
        A1p, AP + W_A10, g64 + 512, b64 + 512, m64 + 512, v64 + 512, occ3, out_f);
}

// Round 14
// 349.751 us; speedup vs baseline: 1.1032x; 1.1032x over previous
//
#include <hip/hip_runtime.h>

#define HW 16384   // 128*128

typedef _Float16 half8  __attribute__((ext_vector_type(8)));
typedef _Float16 half4v __attribute__((ext_vector_type(4)));
typedef float    f32x4  __attribute__((ext_vector_type(4)));

typedef __attribute__((address_space(3))) unsigned int lds_u32;
typedef const __attribute__((address_space(1))) unsigned int glb_u32;

// direct global->LDS 16B DMA (no VGPR round trip)
__device__ __forceinline__ void gl_lds16(const void* g, void* l) {
    __builtin_amdgcn_global_load_lds((glb_u32*)g, (lds_u32*)l, 16, 0, 0);
}

// ---------------- zero fill (float4 granularity) ----------------
__global__ void zero4(float4* __restrict__ p, int n4) {
    int i = blockIdx.x * 256 + threadIdx.x;
    if (i < n4) p[i] = make_float4(0.f, 0.f, 0.f, 0.f);
}

__global__ void write_code_f32(float* out, float v) {
    if (threadIdx.x == 0 && blockIdx.x == 0) out[0] = v;
}

// ---------------- border-only zero: cells with y in {0,129} or x in {0,129} ----------------
__global__ void border_zero(_Float16* __restrict__ base, int D, int CS) {
    int idx = blockIdx.x * 256 + threadIdx.x;
    int gpc = CS / 8;
    int total = D * 516 * gpc;
    if (idx >= total) return;
    int g = idx % gpc;
    int c = (idx / gpc) % 516;
    int d = idx / (gpc * 516);
    int y, x;
    if (c < 130)      { y = 0;           x = c; }
    else if (c < 260) { y = 129;         x = c - 130; }
    else if (c < 388) { y = c - 260 + 1; x = 0; }
    else              { y = c - 388 + 1; x = 129; }
    *(float4*)(base + ((size_t)(d * 130 + y) * 130 + x) * CS + g * 8) =
        make_float4(0.f, 0.f, 0.f, 0.f);
}

// ---------------- fused weight pack: all 11 layers in one dispatch ----------------
// per-unit math identical to the old pack_w (unit = one half8 = 8 f16 of A-frag)
struct PackDesc {
    const float* src[11];
    int dstoff[11];   // f16 offset into AP
    int cum[12];      // cumulative half8-units
    int cinr[11];
    int cinp[11];
    int cout[11];
    int khw[11];
};

__global__ void pack_all(PackDesc pd, _Float16* __restrict__ AP) {
    int u = blockIdx.x * 256 + threadIdx.x;
    if (u >= pd.cum[11]) return;
    int s = 0;
    while (u >= pd.cum[s + 1]) ++s;
    int idx = u - pd.cum[s];
    const int CINr = pd.cinr[s], CINp = pd.cinp[s], KHW = pd.khw[s];
    const int KD = 3;
    const int NSTEPS = KD * KHW * KHW * (CINp / 32);
    const float* W = pd.src[s];
    int lane = idx & 63;
    int st   = (idx >> 6) % NSTEPS;
    int grp  = idx / (NSTEPS * 64);
    int k0  = st * 32 + (lane >> 4) * 8;
    int t   = k0 / CINp;
    int ci0 = k0 % CINp;
    int co  = grp * 16 + (lane & 15);
    int khw2 = KHW * KHW;
    int dz = t / khw2, r = t % khw2, dy = r / KHW, dx = r % KHW;
    half8 hv;
    for (int j = 0; j < 8; ++j) {
        int ci = ci0 + j;
        float wv = (ci < CINr)
            ? W[(((size_t)co * CINr + ci) * KD + dz) * khw2 + dy * KHW + dx] : 0.0f;
        hv[j] = (_Float16)wv;
    }
    *(half8*)(AP + pd.dstoff[s] + ((size_t)(grp * NSTEPS + st) * 64 + lane) * 8) = hv;
}

// ---------------- scatter voxels into [z][130][130][40] f16 grid ----------------
__global__ void scatter_f16(const float* __restrict__ vf, const int* __restrict__ coors,
                            _Float16* __restrict__ act, unsigned char* __restrict__ occ, int n) {
    int i = blockIdx.x * 256 + threadIdx.x;
    if (i >= n) return;
    int z = coors[i * 4 + 1];
    int y = coors[i * 4 + 2];
    int x = coors[i * 4 + 3];
    size_t cell = ((size_t)(z * 130 + (y + 1)) * 130 + (x + 1)) * 40;
    for (int c = 0; c < 16; ++c) act[cell + c] = (_Float16)vf[i * 16 + c];
    occ[z * HW + y * 128 + x] = 1;
}

// ---------------- pool occupancy (u8) over z: D16 -> D8 -> D4 -> D2 ----------------
__global__ void pool_occ(const unsigned char* __restrict__ o0, unsigned char* __restrict__ o1,
                         unsigned char* __restrict__ o2, unsigned char* __restrict__ o3) {
    int p = blockIdx.x * 256 + threadIdx.x;
    if (p >= HW) return;
    unsigned char a[16];
    for (int z = 0; z < 16; ++z) a[z] = o0[z * HW + p];
    for (int z = 0; z < 8; ++z) { a[z] = a[2 * z] | a[2 * z + 1]; o1[z * HW + p] = a[z]; }
    for (int z = 0; z < 4; ++z) { a[z] = a[2 * z] | a[2 * z + 1]; o2[z * HW + p] = a[z]; }
    for (int z = 0; z < 2; ++z) { a[z] = a[2 * z] | a[2 * z + 1]; o3[z * HW + p] = a[z]; }
}

// ---------------- MFMA implicit-GEMM conv + BN + ReLU + occ, LDS-staged ----------------
// act : [DIN][130][130][CS=CINp+8] f16 (y/x padded by 1; border cells' real
//       channels are zero; pad channels never read by compute).
// Staging: global_load_lds 16B granules, LDS layout == linear global stripe.
// out : intermediate [DOUT][130][130][COUT+8] f16 ; FINAL [COUT*2][128][128] f32
// block: 4 waves = 2 output rows x 128 x, each wave = ALL COUT x 64 px.
// XCD-chunked bid swizzle (T1): consecutive (z0,yp) tiles share an XCD's L2.
template <int CINp, int COUT, int KD, int KHW, int SZ, int DIN, int DOUT, bool FINAL>
__global__ __launch_bounds__(256, 2)
void conv_mfma(const _Float16* __restrict__ act, const _Float16* __restrict__ apack,
               const float* __restrict__ gm, const float* __restrict__ bt,
               const float* __restrict__ mn, const float* __restrict__ vr,
               const unsigned char* __restrict__ occ, void* __restrict__ outv) {
    constexpr int PADXY  = KHW / 2;
    constexpr int CB     = CINp / 32;           // 32-k blocks per tap
    constexpr int MG     = COUT / 16;           // co-groups per wave
    constexpr int NSTEPS = KD * KHW * KHW * CB; // total K-steps (for A indexing)
    constexpr int CS     = CINp + 8;            // cell stride (global AND LDS)
    constexpr int OCS    = COUT + 8;            // output cell stride
    constexpr int NGRAN  = 4 * 130 * CS / 8;    // 16B granules per stripe
    constexpr int NIT    = (NGRAN + 255) / 256;
    constexpr int OFS    = 1 - PADXY;           // tap offset correction
    constexpr int NWG    = DOUT * 64;           // grid size (divisible by 8)

    __shared__ _Float16 smem[4 * 130 * CS];

    // XCD-chunked swizzle: hardware assigns bid0 % 8 -> XCD; give each XCD a
    // contiguous (z0,yp) chunk so re-staged rows hit the same L2.
    const int bid0 = blockIdx.x;
    const int bid = (bid0 & 7) * (NWG / 8) + (bid0 >> 3);
    const int yp = bid & 63;
    const int z0 = bid >> 6;
    const int y0 = yp * 2;
    const int tid  = threadIdx.x;
    const int w    = tid >> 6;
    const int lane = tid & 63;
    const int ylocal = w >> 1;       // 0..1
    const int x0w    = (w & 1) * 64; // 0 or 64
    const int n  = lane & 15;
    const int kg = lane >> 4;

    f32x4 acc[MG][4];
    #pragma unroll
    for (int m = 0; m < MG; ++m)
        #pragma unroll
        for (int t = 0; t < 4; ++t) { acc[m][t][0] = 0.f; acc[m][t][1] = 0.f; acc[m][t][2] = 0.f; acc[m][t][3] = 0.f; }

    const int zb = z0 * SZ;
    const int dzlo = (zb == 0) ? 1 : 0;
    const int dzhi = (zb + KD - 1 > DIN) ? (KD - 1) : KD;

    for (int dz = dzlo; dz < dzhi; ++dz) {
        const int zi = zb + dz - 1;
        __syncthreads();   // previous iteration's LDS reads complete
        // ---- stage stripe via global_load_lds (linear copy, 16B granules) ----
        const _Float16* src = act + (size_t)(zi * 130 + y0) * (130 * CS);
        #pragma unroll
        for (int it = 0; it < NIT; ++it) {
            int g = it * 256 + tid;
            if (g < NGRAN) gl_lds16(src + (size_t)g * 8, smem + (size_t)g * 8);
        }
        asm volatile("s_waitcnt vmcnt(0)" ::: "memory");
        __syncthreads();
        // ---- K-loop over taps (straight-line) ----
        #pragma unroll
        for (int dy = 0; dy < KHW; ++dy) {
            #pragma unroll
            for (int dx = 0; dx < KHW; ++dx) {
                #pragma unroll
                for (int cb = 0; cb < CB; ++cb) {
                    const int sabs = dz * (KHW * KHW * CB) + (dy * KHW + dx) * CB + cb;
                    half8 a[MG];
                    #pragma unroll
                    for (int mg = 0; mg < MG; ++mg)
                        a[mg] = *(const half8*)(apack + ((size_t)(mg * NSTEPS + sabs) * 64 + lane) * 8);
                    const _Float16* bp = smem
                        + ((ylocal + dy + OFS) * 130 + x0w + n + dx + OFS) * CS + cb * 32 + kg * 8;
                    #pragma unroll
                    for (int nt = 0; nt < 4; ++nt) {
                        half8 b = *(const half8*)(bp + nt * 16 * CS);
                        #pragma unroll
                        for (int mg = 0; mg < MG; ++mg)
                            acc[mg][nt] = __builtin_amdgcn_mfma_f32_16x16x32_f16(a[mg], b, acc[mg][nt], 0, 0, 0);
                    }
                }
            }
        }
    }

    // ---- epilogue: BN + ReLU + occ, store ----
    const int yo = y0 + ylocal;
    #pragma unroll
    for (int mg = 0; mg < MG; ++mg) {
        const int co0 = mg * 16 + kg * 4;
        const f32x4 gv = *(const f32x4*)(gm + co0);
        const f32x4 bv = *(const f32x4*)(bt + co0);
        const f32x4 mv = *(const f32x4*)(mn + co0);
        const f32x4 vv = *(const f32x4*)(vr + co0);
        float sc[4], sh[4];
        #pragma unroll
        for (int r = 0; r < 4; ++r) {
            sc[r] = gv[r] * __frsqrt_rn(vv[r] + 1e-5f);
            sh[r] = bv[r] - mv[r] * sc[r];
        }
        #pragma unroll
        for (int nt = 0; nt < 4; ++nt) {
            const int x = x0w + nt * 16 + n;
            const float occv = (float)occ[z0 * HW + yo * 128 + x];
            float v0 = fmaxf(fmaf(acc[mg][nt][0], sc[0], sh[0]), 0.f) * occv;
            float v1 = fmaxf(fmaf(acc[mg][nt][1], sc[1], sh[1]), 0.f) * occv;
            float v2 = fmaxf(fmaf(acc[mg][nt][2], sc[2], sh[2]), 0.f) * occv;
            float v3 = fmaxf(fmaf(acc[mg][nt][3], sc[3], sh[3]), 0.f) * occv;
            if constexpr (FINAL) {
                float* o = (float*)outv;
                const int sp = yo * 128 + x;
                o[((size_t)(co0 + 0) * 2 + z0) * HW + sp] = v0;
                o[((size_t)(co0 + 1) * 2 + z0) * HW + sp] = v1;
                o[((size_t)(co0 + 2) * 2 + z0) * HW + sp] = v2;
                o[((size_t)(co0 + 3) * 2 + z0) * HW + sp] = v3;
            } else {
                _Float16* o = (_Float16*)outv;
                half4v hv;
                hv[0] = (_Float16)v0; hv[1] = (_Float16)v1;
                hv[2] = (_Float16)v2; hv[3] = (_Float16)v3;
                *(half4v*)(o + ((size_t)(z0 * 130 + (yo + 1)) * 130 + (x + 1)) * OCS + co0) = hv;
            }
        }
    }
}

extern "C" void kernel_launch(void* const* d_in, const int* in_sizes, int n_in,
                              void* d_out, int out_size, void* d_ws, size_t ws_size,
                              hipStream_t stream) {
    const float* vf    = (const float*)d_in[0];
    const int*   coors = (const int*)d_in[1];
    const float* w0    = (const float*)d_in[2];
    const float* w1    = (const float*)d_in[3];
    const float* w2    = (const float*)d_in[4];
    const float* w64   = (const float*)d_in[5];
    const float* w10   = (const float*)d_in[6];
    const float* g32   = (const float*)d_in[7];
    const float* b32   = (const float*)d_in[8];
    const float* m32   = (const float*)d_in[9];
    const float* v32   = (const float*)d_in[10];
    const float* g64   = (const float*)d_in[11];
    const float* b64   = (const float*)d_in[12];
    const float* m64   = (const float*)d_in[13];
    const float* v64   = (const float*)d_in[14];
    const int N = in_sizes[0] / 16;

    float* out_f = (float*)d_out;

    // ---- workspace layout (bytes) ----
    // S32   = 16*130*130*40*2 = 21,632,000  (P32 layers, D16)
    // S64_8 =  8*130*130*72*2 = 19,468,800  (P64 layers, D8)
    // S64_4 =  4*130*130*72*2 =  9,734,400  (P64 layers, D4)
    // R2 aliases R1 (P32 dead after L1); D4A/D4B alias R0/R1 fronts.
    const size_t R0 = 0;
    const size_t R1 = 21632000;
    const size_t R3 = 43264000;
    const size_t OFF_OCC0 = 62732800;   // u8 [16][HW]
    const size_t OFF_OCC1 = 62994944;   // u8 [8][HW]
    const size_t OFF_OCC2 = 63126016;   // u8 [4][HW]
    const size_t OFF_OCC3 = 63191552;   // u8 [2][HW]
    const size_t OFF_AP   = 63224320;   // f16 packed weights (897,024 el)
    const size_t TOTAL_BYTES = 65018368;

    if (ws_size < TOTAL_BYTES) {
        write_code_f32<<<dim3(1), dim3(64), 0, stream>>>(out_f, 1.0e8f);
        return;
    }

    char* wsb = (char*)d_ws;
    _Float16* A0p = (_Float16*)(wsb + R0);   // P32 A ; front = D4A
    _Float16* A1p = (_Float16*)(wsb + R1);   // P32 B ; also R2 (P64 D8) ; front = D4B
    _Float16* A3p = (_Float16*)(wsb + R3);   // P64 D8
    _Float16* A2p = A1p;                     // R2 alias
    unsigned char* occ0 = (unsigned char*)(wsb + OFF_OCC0);
    unsigned char* occ1 = (unsigned char*)(wsb + OFF_OCC1);
    unsigned char* occ2 = (unsigned char*)(wsb + OFF_OCC2);
    unsigned char* occ3 = (unsigned char*)(wsb + OFF_OCC3);
    _Float16* AP = (_Float16*)(wsb + OFF_AP);

    const size_t W_A0 = 0, W_A1 = 27648, W_A2 = 55296, W_A3 = 110592, W_A10 = 884736;

    // ---- prologue zeroing: R0 full (scatter target), borders elsewhere ----
    zero4<<<dim3((21632000 / 16 + 255) / 256), dim3(256), 0, stream>>>((float4*)(wsb + R0), 21632000 / 16);
    zero4<<<dim3((262144 / 16 + 255) / 256), dim3(256), 0, stream>>>((float4*)occ0, 262144 / 16);
    {   // R1 borders @ D16/CS40 ; R3 borders @ D8/CS72
        int t1 = 16 * 516 * (40 / 8);
        border_zero<<<dim3((t1 + 255) / 256), dim3(256), 0, stream>>>(A1p, 16, 40);
        int t3 = 8 * 516 * (72 / 8);
        border_zero<<<dim3((t3 + 255) / 256), dim3(256), 0, stream>>>(A3p, 8, 72);
    }

    // ---- fused weight pack (single dispatch) ----
    {
        PackDesc pd;
        int units[11] = {3456, 3456, 6912, 13824, 13824, 13824, 13824, 13824, 13824, 13824, 1536};
        const float* srcs[11] = {w0, w1, w2,
                                 w64 + 0 * 110592, w64 + 1 * 110592, w64 + 2 * 110592,
                                 w64 + 3 * 110592, w64 + 4 * 110592, w64 + 5 * 110592,
                                 w64 + 6 * 110592, w10};
        int offs[11] = {(int)W_A0, (int)W_A1, (int)W_A2,
                        (int)(W_A3 + 0 * 110592), (int)(W_A3 + 1 * 110592), (int)(W_A3 + 2 * 110592),
                        (int)(W_A3 + 3 * 110592), (int)(W_A3 + 4 * 110592), (int)(W_A3 + 5 * 110592),
                        (int)(W_A3 + 6 * 110592), (int)W_A10};
        int cinr[11] = {16, 32, 32, 64, 64, 64, 64, 64, 64, 64, 64};
        int cinp[11] = {32, 32, 32, 64, 64, 64, 64, 64, 64, 64, 64};
        int cout[11] = {32, 32, 64, 64, 64, 64, 64, 64, 64, 64, 64};
        int khw[11]  = {3, 3, 3, 3, 3, 3, 3, 3, 3, 3, 1};
        int c = 0;
        for (int i = 0; i < 11; ++i) {
            pd.src[i] = srcs[i]; pd.dstoff[i] = offs[i]; pd.cum[i] = c; c += units[i];
            pd.cinr[i] = cinr[i]; pd.cinp[i] = cinp[i]; pd.cout[i] = cout[i]; pd.khw[i] = khw[i];
        }
        pd.cum[11] = c;   // 112128
        pack_all<<<dim3((c + 255) / 256), dim3(256), 0, stream>>>(pd, AP);
    }

    scatter_f16<<<dim3((N + 255) / 256), dim3(256), 0, stream>>>(vf, coors, A0p, occ0, N);
    pool_occ<<<dim3(HW / 256), dim3(256), 0, stream>>>(occ0, occ1, occ2, occ3);

    // L0: 16(pad32)->32, D16  (R0 -> R1)
    conv_mfma<32, 32, 3, 3, 1, 16, 16, false><<<dim3(16 * 64), dim3(256), 0, stream>>>(
        A0p, AP + W_A0, g32, b32, m32, v32, occ0, A1p);
    // L1: 32->32, D16  (R1 -> R0)
    conv_mfma<32, 32, 3, 3, 1, 16, 16, false><<<dim3(16 * 64), dim3(256), 0, stream>>>(
        A1p, AP + W_A1, g32 + 32, b32 + 32, m32 + 32, v32 + 32, occ0, A0p);
    // R1's P32 data dead -> zero R2's borders (D8/CS72 geometry)
    {
        int t = 8 * 516 * (72 / 8);
        border_zero<<<dim3((t + 255) / 256), dim3(256), 0, stream>>>(A2p, 8, 72);
    }
    // L2: 32->64, stride-z 2, D16->8  (R0 -> R2)
    conv_mfma<32, 64, 3, 3, 2, 16, 8, false><<<dim3(8 * 64), dim3(256), 0, stream>>>(
        A0p, AP + W_A2, g64, b64, m64, v64, occ1, A2p);
    // R0 dead -> zero D4A borders (D4/CS72)
    {
        int t = 4 * 516 * (72 / 8);
        border_zero<<<dim3((t + 255) / 256), dim3(256), 0, stream>>>(A0p, 4, 72);
    }
    // L3..L5: 64->64, D8  (R2 -> R3 -> R2 -> R3)
    conv_mfma<64, 64, 3, 3, 1, 8, 8, false><<<dim3(8 * 64), dim3(256), 0, stream>>>(
        A2p, AP + W_A3 + 0 * 110592, g64 + 64, b64 + 64, m64 + 64, v64 + 64, occ1, A3p);
    conv_mfma<64, 64, 3, 3, 1, 8, 8, false><<<dim3(8 * 64), dim3(256), 0, stream>>>(
        A3p, AP + W_A3 + 1 * 110592, g64 + 128, b64 + 128, m64 + 128, v64 + 128, occ1, A2p);
    conv_mfma<64, 64, 3, 3, 1, 8, 8, false><<<dim3(8 * 64), dim3(256), 0, stream>>>(
        A2p, AP + W_A3 + 2 * 110592, g64 + 192, b64 + 192, m64 + 192, v64 + 192, occ1, A3p);
    // L6: 64->64, stride-z 2, D8->4  (R3 -> D4A)
    conv_mfma<64, 64, 3, 3, 2, 8, 4, false><<<dim3(4 * 64), dim3(256), 0, stream>>>(
        A3p, AP + W_A3 + 3 * 110592, g64 + 256, b64 + 256, m64 + 256, v64 + 256, occ2, A0p);
    // R2 dead (after L5) -> zero D4B borders (D4/CS72)
    {
        int t = 4 * 516 * (72 / 8);
        border_zero<<<dim3((t + 255) / 256), dim3(256), 0, stream>>>(A1p, 4, 72);
    }
    // L7..L9: 64->64, D4  (D4A -> D4B -> D4A -> D4B)
    conv_mfma<64, 64, 3, 3, 1, 4, 4, false><<<dim3(4 * 64), dim3(256), 0, stream>>>(
        A0p, AP + W_A3 + 4 * 110592, g64 + 320, b64 + 320, m64 + 320, v64 + 320, occ2, A1p);
    conv_mfma<64, 64, 3, 3, 1, 4, 4, false><<<dim3(4 * 64), dim3(256), 0, stream>>>(
        A1p, AP + W_A3 + 5 * 110592, g64 + 384, b64 + 384, m64 + 384, v64 + 384, occ2, A0p);
    conv_mfma<64, 64, 3, 3, 1, 4, 4, false><<<dim3(4 * 64), dim3(256), 0, stream>>>(
        A0p, AP + W_A3 + 6 * 110592, g64 + 448, b64 + 448, m64 + 448, v64 + 448, occ2, A1p);
    // L10: 64->64, kernel (3,1,1), stride-z 2, D4->2, f32 out -> d_out  (D4B -> out)
    conv_mfma<64, 64, 3, 1, 2, 4, 2, true><<<dim3(2 * 64), dim3(256), 0, stream>>>(
        A1p, AP + W_A10, g64 + 512, b64 + 512, m64 + 512, v64 + 512, occ3, out_f);
}